// Round 1
// baseline (767.243 us; speedup 1.0000x reference)
//
#include <hip/hip_runtime.h>
#include <hip/hip_bf16.h>
#include <math.h>

typedef unsigned short bhalf;
typedef __attribute__((ext_vector_type(8))) short s16x8;
typedef __attribute__((ext_vector_type(4))) float f32x4;

#define SCALE_QK 0.15811388300841898f

__device__ __forceinline__ float bf2f(bhalf u){
    union { unsigned int i; float f; } v; v.i = ((unsigned int)u) << 16; return v.f;
}
__device__ __forceinline__ bhalf f2bf(float f){
    unsigned int x = __float_as_uint(f);
    unsigned int r = (x + 0x7fffu + ((x >> 16) & 1u)) >> 16;
    return (bhalf)r;
}

// ---------------------------------------------------------------- weight prep
struct WB8 { const float* in[8]; bhalf* out[8]; };

__global__ void transpose_w(WB8 wb, int K, int cnt){
    const int per = 320 * K;
    for (int idx = blockIdx.x * 256 + threadIdx.x; idx < cnt * per; idx += gridDim.x * 256){
        const int w = idx / per, rem = idx % per;
        const int n = rem / K, k = rem % K;
        wb.out[w][rem] = f2bf(wb.in[w][(long)k * 320 + n]);
    }
}

// ---------------------------------------------------------------- resize (8x down, half-pixel bilinear -> 4-tap avg)
__global__ void resize_kernel(const float* __restrict__ gm, const float* __restrict__ supp,
                              const float* __restrict__ sgv, float* __restrict__ gm_all,
                              float* __restrict__ sig){
    const int i = blockIdx.x * 256 + threadIdx.x;
    if (i >= 4096) return;
    const int y = i >> 6, x = i & 63;
    const int o = (8 * y + 3) * 512 + 8 * x + 3;
#pragma unroll
    for (int p = 0; p < 4; ++p){
        const float* s = gm + (long)p * 262144;
        gm_all[p * 4096 + i] = 0.25f * (s[o] + s[o + 1] + s[o + 512] + s[o + 513]);
    }
    gm_all[4 * 4096 + i] = 0.25f * (supp[o] + supp[o + 1] + supp[o + 512] + supp[o + 513]);
#pragma unroll
    for (int p = 0; p < 4; ++p){
        const float* s = sgv + (long)p * 262144;
        sig[p * 4096 + i] = 0.25f * (s[o] + s[o + 1] + s[o + 512] + s[o + 513]);
    }
}

// ---------------------------------------------------------------- PositionNet (fourier + 3-layer MLP), one block per box
__global__ __launch_bounds__(768) void posnet_kernel(
    const float* __restrict__ box,
    const float* __restrict__ W1, const float* __restrict__ b1,
    const float* __restrict__ W2, const float* __restrict__ b2,
    const float* __restrict__ W3, const float* __restrict__ b3,
    float* __restrict__ tok)
{
    const int bb = blockIdx.x, t = threadIdx.x;
    __shared__ float emb[128], h1[512], h2[512];
    if (t < 128){
        const int i = t >> 4, jj = t & 15, j = jj & 7;
        const float f = powf(100.f, (float)i * 0.125f);
        const float v = f * box[bb * 8 + j];
        emb[t] = (jj < 8) ? sinf(v) : cosf(v);
    }
    __syncthreads();
    if (t < 512){
        float a = b1[t];
        for (int k = 0; k < 128; ++k) a += emb[k] * W1[k * 512 + t];
        h1[t] = a / (1.f + __expf(-a));
    }
    __syncthreads();
    if (t < 512){
        float a = b2[t];
        for (int k = 0; k < 512; ++k) a += h1[k] * W2[k * 512 + t];
        h2[t] = a / (1.f + __expf(-a));
    }
    __syncthreads();
    {
        float a = b3[t];
        for (int k = 0; k < 512; ++k) a += h2[k] * W3[k * 768 + t];
        tok[bb * 768 + t] = a;
    }
}

// ---------------------------------------------------------------- context assembly (f32 -> bf16)
__global__ void assemble_fg(const float* __restrict__ context, const float* __restrict__ imgf,
                            const float* __restrict__ boxtok, bhalf* __restrict__ out){
    const int idx = blockIdx.x * 256 + threadIdx.x;
    if (idx >= 4 * 336 * 768) return;
    const int i = idx / (336 * 768);
    const int r = (idx / 768) % 336;
    const int c = idx % 768;
    float v;
    if (r < 77)       v = context[((long)(1 + i) * 77 + r) * 768 + c];
    else if (r < 334) v = imgf[((long)i * 257 + (r - 77)) * 768 + c];
    else if (r == 334) v = boxtok[i * 768 + c];
    else v = 0.f;
    out[idx] = f2bf(v);
}
__global__ void assemble_bg(const float* __restrict__ context, const float* __restrict__ bgf,
                            bhalf* __restrict__ out){
    const int idx = blockIdx.x * 256 + threadIdx.x;
    if (idx >= 336 * 768) return;
    const int r = idx / 768, c = idx % 768;
    float v;
    if (r < 77)       v = context[(long)r * 768 + c];
    else if (r < 334) v = bgf[(long)(r - 77) * 768 + c];
    else v = 0.f;
    out[idx] = f2bf(v);
}

// ---------------------------------------------------------------- LayerNorm over C=320, one block per row
__global__ __launch_bounds__(320) void ln_kernel(
    const float* __restrict__ in, const float* __restrict__ g, const float* __restrict__ b,
    bhalf* __restrict__ out)
{
    const int row = blockIdx.x, c = threadIdx.x;
    const float v = in[(long)row * 320 + c];
    float s = v, sq = v * v;
#pragma unroll
    for (int o = 1; o < 64; o <<= 1){ s += __shfl_xor(s, o); sq += __shfl_xor(sq, o); }
    __shared__ float rs[5], rq[5];
    const int wv = threadIdx.x >> 6;
    if ((threadIdx.x & 63) == 0){ rs[wv] = s; rq[wv] = sq; }
    __syncthreads();
    if (threadIdx.x == 0){
        float ts = 0, tq = 0;
#pragma unroll
        for (int w = 0; w < 5; ++w){ ts += rs[w]; tq += rq[w]; }
        rs[0] = ts; rq[0] = tq;
    }
    __syncthreads();
    const float mean = rs[0] * (1.f / 320.f);
    const float var  = rq[0] * (1.f / 320.f) - mean * mean;
    const float inv  = rsqrtf(var + 1e-5f);
    out[(long)row * 320 + c] = f2bf((v - mean) * inv * g[c] + b[c]);
}

// S = sum_i sig_i * (ca_x[1+i] + ea_i), then q2 = LN(S)
__global__ __launch_bounds__(320) void s_ln_kernel(
    const float* __restrict__ ca_x, const float* __restrict__ ea, const float* __restrict__ sig,
    const float* __restrict__ g, const float* __restrict__ b,
    float* __restrict__ S, bhalf* __restrict__ q2)
{
    const int hw = blockIdx.x, c = threadIdx.x;
    float v = 0.f;
#pragma unroll
    for (int i = 0; i < 4; ++i){
        const float sg = sig[i * 4096 + hw];
        v += sg * (ca_x[((long)(1 + i) * 4096 + hw) * 320 + c] + ea[((long)i * 4096 + hw) * 320 + c]);
    }
    S[(long)hw * 320 + c] = v;
    float s = v, sq = v * v;
#pragma unroll
    for (int o = 1; o < 64; o <<= 1){ s += __shfl_xor(s, o); sq += __shfl_xor(sq, o); }
    __shared__ float rs[5], rq[5];
    const int wv = threadIdx.x >> 6;
    if ((threadIdx.x & 63) == 0){ rs[wv] = s; rq[wv] = sq; }
    __syncthreads();
    if (threadIdx.x == 0){
        float ts = 0, tq = 0;
#pragma unroll
        for (int w = 0; w < 5; ++w){ ts += rs[w]; tq += rq[w]; }
        rs[0] = ts; rq[0] = tq;
    }
    __syncthreads();
    const float mean = rs[0] * (1.f / 320.f);
    const float var  = rq[0] * (1.f / 320.f) - mean * mean;
    const float inv  = rsqrtf(var + 1e-5f);
    q2[(long)hw * 320 + c] = f2bf((v - mean) * inv * g[c] + b[c]);
}

__global__ void f2bf_kernel(const float* __restrict__ in, bhalf* __restrict__ out, int n){
    const int i = blockIdx.x * 256 + threadIdx.x;
    if (i < n) out[i] = f2bf(in[i]);
}

// ---------------------------------------------------------------- generic GEMM: C[M][320] = A[M][K] @ Wt[320][K]^T
// LDS-free: A-frags and Wt-frags read directly (16B contiguous per lane); weights L2-resident.
// MODE 0: bf16 out.  1: bf16 V-transposed out.  2: f32 out + bias.
// MODE 3: f32 out = acc+bias+add1+add2.  4: f32 out += acc+bias.
template<int MODE>
__global__ __launch_bounds__(256) void gemm320(
    const bhalf* __restrict__ A, const bhalf* __restrict__ Wt,
    const float* __restrict__ bias, bhalf* __restrict__ Cbf,
    float* __restrict__ Cf, const float* __restrict__ add1, const float* __restrict__ add2,
    int M, int K, int vt_mod, long vt_istride, int vt_cstride)
{
    const int wave = threadIdx.x >> 6, lane = threadIdx.x & 63;
    const int m0 = blockIdx.x * 64 + wave * 16;
    const int n0 = blockIdx.y * 64;
    int mrow = m0 + (lane & 15); if (mrow > M - 1) mrow = M - 1;
    const int klo = (lane >> 4) * 8;
    const bhalf* ap = A + (long)mrow * K + klo;
    const bhalf* wp = Wt + (long)(n0 + (lane & 15)) * K + klo;
    const f32x4 fz = {0.f, 0.f, 0.f, 0.f};
    f32x4 acc[4]; acc[0] = fz; acc[1] = fz; acc[2] = fz; acc[3] = fz;
    for (int k0 = 0; k0 < K; k0 += 32){
        s16x8 a = *(const s16x8*)(ap + k0);
#pragma unroll
        for (int t = 0; t < 4; ++t){
            s16x8 b = *(const s16x8*)(wp + (long)t * 16 * K + k0);
            acc[t] = __builtin_amdgcn_mfma_f32_16x16x32_bf16(a, b, acc[t], 0, 0, 0);
        }
    }
    const int rb = m0 + (lane >> 4) * 4;
#pragma unroll
    for (int t = 0; t < 4; ++t){
        const int col = n0 + t * 16 + (lane & 15);
#pragma unroll
        for (int r = 0; r < 4; ++r){
            const int row = rb + r;
            if (row >= M) continue;
            const float v = acc[t][r];
            if (MODE == 0) Cbf[(long)row * 320 + col] = f2bf(v);
            else if (MODE == 1) Cbf[(long)(row / vt_mod) * vt_istride + (long)col * vt_cstride + (row % vt_mod)] = f2bf(v);
            else if (MODE == 2) Cf[(long)row * 320 + col] = v + bias[col];
            else if (MODE == 3){ const long o = (long)row * 320 + col; Cf[o] = v + bias[col] + add1[o] + add2[o]; }
            else { const long o = (long)row * 320 + col; Cf[o] += v + bias[col]; }
        }
    }
}

// ---------------------------------------------------------------- flash attention, DH=40 (K=32 + predicated 8-tail)
// block = 4 waves, each wave owns 16 q-rows with a private LDS score strip [16][NC+8] (bf16).
// Online softmax (4 lanes per row, shfl reductions). GMM: guidance-mask sparsity (keep iff dot5 != 0).
template<int NC, bool GMM>
__global__ __launch_bounds__(256) void flash_attn(
    const bhalf* __restrict__ Q, const bhalf* __restrict__ Kc, const bhalf* __restrict__ Vt,
    bhalf* __restrict__ O, const float* __restrict__ gm_all,
    int NKV, long q_is, long k_is, long vt_is, int vt_ns)
{
    __shared__ bhalf P[64][NC + 8];
    const int wave = threadIdx.x >> 6, lane = threadIdx.x & 63;
    const int h = blockIdx.y, inst = blockIdx.z;
    const int q0 = blockIdx.x * 64 + wave * 16;
    const int klo = (lane >> 4) * 8;
    const int l15 = lane & 15;
    const s16x8 z8 = {0, 0, 0, 0, 0, 0, 0, 0};
    const f32x4 fz = {0.f, 0.f, 0.f, 0.f};

    const bhalf* qp = Q + inst * q_is + (long)(q0 + l15) * 320 + h * 40;
    const s16x8 qa0 = *(const s16x8*)(qp + klo);
    const s16x8 qa1 = (klo == 0) ? *(const s16x8*)(qp + 32) : z8;

    float gq[5][4];
    if (GMM){
#pragma unroll
        for (int p = 0; p < 5; ++p)
#pragma unroll
            for (int r = 0; r < 4; ++r)
                gq[p][r] = gm_all[p * 4096 + q0 + (lane >> 4) * 4 + r];
    }

    f32x4 acc[3]; acc[0] = fz; acc[1] = fz; acc[2] = fz;
    const int srow = lane >> 2, sq = lane & 3;
    float m_run = -3.402823466e38f, l_run = 0.f;
    const int nchunks = (NKV + NC - 1) / NC;

    for (int ch = 0; ch < nchunks; ++ch){
        const int c0 = ch * NC;
        // ---- QK^T -> bf16 scores in LDS (masked -> -FLT_MAX)
        for (int t = 0; t < NC / 16; ++t){
            const int n = c0 + t * 16 + l15;
            const bool nv = n < NKV;
            const bhalf* kp = Kc + inst * k_is + (long)n * 320 + h * 40;
            const s16x8 kb0 = nv ? *(const s16x8*)(kp + klo) : z8;
            const s16x8 kb1 = (nv && klo == 0) ? *(const s16x8*)(kp + 32) : z8;
            f32x4 d = fz;
            d = __builtin_amdgcn_mfma_f32_16x16x32_bf16(qa0, kb0, d, 0, 0, 0);
            d = __builtin_amdgcn_mfma_f32_16x16x32_bf16(qa1, kb1, d, 0, 0, 0);
            float gk[5];
            if (GMM){
#pragma unroll
                for (int p = 0; p < 5; ++p) gk[p] = gm_all[p * 4096 + n];
            }
#pragma unroll
            for (int r = 0; r < 4; ++r){
                bool keep = nv;
                if (GMM && keep){
                    const float dot = gq[0][r] * gk[0] + gq[1][r] * gk[1] + gq[2][r] * gk[2]
                                    + gq[3][r] * gk[3] + gq[4][r] * gk[4];
                    keep = (dot != 0.f);
                }
                P[wave * 16 + (lane >> 4) * 4 + r][t * 16 + l15] =
                    keep ? f2bf(d[r] * SCALE_QK) : (bhalf)0xFF7F;
            }
        }
        __syncthreads();
        // ---- online softmax (4 lanes per row)
        bhalf* prow = &P[wave * 16 + srow][0];
        float cmax = -3.402823466e38f;
#pragma unroll
        for (int t = 0; t < NC / 32; ++t){
            const s16x8 v = *(const s16x8*)(prow + sq * 8 + t * 32);
#pragma unroll
            for (int j = 0; j < 8; ++j) cmax = fmaxf(cmax, bf2f((bhalf)v[j]));
        }
        cmax = fmaxf(cmax, __shfl_xor(cmax, 1));
        cmax = fmaxf(cmax, __shfl_xor(cmax, 2));
        const float mnew = fmaxf(m_run, cmax);
        const float fac = __expf(m_run - mnew);
        float csum = 0.f;
#pragma unroll
        for (int t = 0; t < NC / 32; ++t){
            bhalf* pp = prow + sq * 8 + t * 32;
            const s16x8 v = *(const s16x8*)pp;
            s16x8 wv;
#pragma unroll
            for (int j = 0; j < 8; ++j){
                const float p = __expf(bf2f((bhalf)v[j]) - mnew);
                csum += p;
                wv[j] = (short)f2bf(p);
            }
            *(s16x8*)pp = wv;
        }
        csum += __shfl_xor(csum, 1);
        csum += __shfl_xor(csum, 2);
        l_run = l_run * fac + csum;
        m_run = mnew;
        __syncthreads();
        // ---- rescale accumulators
#pragma unroll
        for (int r = 0; r < 4; ++r){
            const float fr = __shfl(fac, ((lane >> 4) * 4 + r) * 4);
            acc[0][r] *= fr; acc[1][r] *= fr; acc[2][r] *= fr;
        }
        // ---- P @ V (V transposed: Vt[channel][n])
#pragma unroll
        for (int ct = 0; ct < 3; ++ct){
            const bhalf* vp = Vt + inst * vt_is + (long)(h * 40 + ct * 16 + l15) * vt_ns + c0 + klo;
            for (int ks = 0; ks < NC / 32; ++ks){
                const s16x8 pa = *(const s16x8*)(&P[wave * 16 + l15][ks * 32 + klo]);
                const s16x8 vb = *(const s16x8*)(vp + ks * 32);
                acc[ct] = __builtin_amdgcn_mfma_f32_16x16x32_bf16(pa, vb, acc[ct], 0, 0, 0);
            }
        }
        __syncthreads();
    }
    // ---- normalize + write
#pragma unroll
    for (int r = 0; r < 4; ++r){
        const float lr = __shfl(l_run, ((lane >> 4) * 4 + r) * 4);
        const float inv = 1.f / lr;
        const int row = q0 + (lane >> 4) * 4 + r;
        bhalf* op = O + inst * q_is + (long)row * 320 + h * 40;
#pragma unroll
        for (int ct = 0; ct < 3; ++ct){
            const int c = ct * 16 + l15;
            if (c < 40) op[c] = f2bf(acc[ct][r] * inv);
        }
    }
}

// ================================================================ host
extern "C" void kernel_launch(void* const* d_in, const int* in_sizes, int n_in,
                              void* d_out, int out_size, void* d_ws, size_t ws_size,
                              hipStream_t stream)
{
    (void)in_sizes; (void)n_in; (void)out_size; (void)ws_size;
    const float* ca_x   = (const float*)d_in[0];
    const float* gmask  = (const float*)d_in[1];
    const float* smask  = (const float*)d_in[2];
    const float* itok   = (const float*)d_in[3];
    const float* ctx    = (const float*)d_in[4];
    const float* box    = (const float*)d_in[5];
    const float* imgf   = (const float*)d_in[6];
    const float* bgf    = (const float*)d_in[7];
    const float* sgv    = (const float*)d_in[8];
    const float* Wq_obj = (const float*)d_in[9];
    const float* Wk_obj = (const float*)d_in[10];
    const float* Wv_obj = (const float*)d_in[11];
    const float* Wo_obj = (const float*)d_in[12];
    const float* bo_obj = (const float*)d_in[13];
    const float* g_obj  = (const float*)d_in[14];
    const float* b_obj  = (const float*)d_in[15];
    const float* Wq2    = (const float*)d_in[16];
    const float* Wk2    = (const float*)d_in[17];
    const float* Wv2    = (const float*)d_in[18];
    const float* Wo2    = (const float*)d_in[19];
    const float* bo2    = (const float*)d_in[20];
    const float* g2     = (const float*)d_in[21];
    const float* b2     = (const float*)d_in[22];
    const float* pnW1   = (const float*)d_in[23];
    const float* pnb1   = (const float*)d_in[24];
    const float* pnW2   = (const float*)d_in[25];
    const float* pnb2   = (const float*)d_in[26];
    const float* pnW3   = (const float*)d_in[27];
    const float* pnb3   = (const float*)d_in[28];
    const float* laWq   = (const float*)d_in[29];
    const float* laWk   = (const float*)d_in[30];
    const float* laWv   = (const float*)d_in[31];
    const float* laWo   = (const float*)d_in[32];
    const float* labo   = (const float*)d_in[33];

    char* wsp = (char*)d_ws; size_t off = 0;
    auto alloc = [&](size_t bytes) -> void* {
        void* p = wsp + off; off += (bytes + 255) & ~(size_t)255; return p;
    };
    bhalf* wqobjT = (bhalf*)alloc(320 * 320 * 2);
    bhalf* woobjT = (bhalf*)alloc(320 * 320 * 2);
    bhalf* wq2T   = (bhalf*)alloc(320 * 320 * 2);
    bhalf* wo2T   = (bhalf*)alloc(320 * 320 * 2);
    bhalf* lawqT  = (bhalf*)alloc(320 * 320 * 2);
    bhalf* lawkT  = (bhalf*)alloc(320 * 320 * 2);
    bhalf* lawvT  = (bhalf*)alloc(320 * 320 * 2);
    bhalf* lawoT  = (bhalf*)alloc(320 * 320 * 2);
    bhalf* wkobjT = (bhalf*)alloc(768 * 320 * 2);
    bhalf* wvobjT = (bhalf*)alloc(768 * 320 * 2);
    bhalf* wk2T   = (bhalf*)alloc(768 * 320 * 2);
    bhalf* wv2T   = (bhalf*)alloc(768 * 320 * 2);
    float* gm_all = (float*)alloc(5 * 4096 * 4);
    float* sig    = (float*)alloc(4 * 4096 * 4);
    float* boxtok = (float*)alloc(4 * 768 * 4);
    bhalf* ctx_fg = (bhalf*)alloc((size_t)4 * 336 * 768 * 2);
    bhalf* ctx_bg = (bhalf*)alloc((size_t)336 * 768 * 2);
    bhalf* q_in   = (bhalf*)alloc((size_t)16384 * 320 * 2);
    bhalf* x_la   = (bhalf*)alloc((size_t)4096 * 320 * 2);
    bhalf* k_obj  = (bhalf*)alloc((size_t)4 * 336 * 320 * 2);
    bhalf* vt_obj = (bhalf*)alloc((size_t)4 * 336 * 352 * 2);
    bhalf* k_bg   = (bhalf*)alloc((size_t)336 * 320 * 2);
    bhalf* vt_bg  = (bhalf*)alloc((size_t)336 * 352 * 2);
    bhalf* q_obj  = (bhalf*)alloc((size_t)16384 * 320 * 2);
    bhalf* o_obj  = (bhalf*)alloc((size_t)16384 * 320 * 2);
    float* ea     = (float*)alloc((size_t)16384 * 320 * 4);
    float* Sbuf   = (float*)alloc((size_t)4096 * 320 * 4);
    bhalf* q2v    = (bhalf*)alloc((size_t)4096 * 320 * 2);
    bhalf* q2p    = (bhalf*)alloc((size_t)4096 * 320 * 2);
    bhalf* o2     = (bhalf*)alloc((size_t)4096 * 320 * 2);
    bhalf* ql     = (bhalf*)alloc((size_t)4096 * 320 * 2);
    bhalf* kl     = (bhalf*)alloc((size_t)4096 * 320 * 2);
    bhalf* vt_l   = (bhalf*)alloc((size_t)336 * 4096 * 2);
    bhalf* ol     = (bhalf*)alloc((size_t)4096 * 320 * 2);

    // weight transposes (bf16, [N][K])
    WB8 wa{};
    wa.in[0] = Wq_obj; wa.out[0] = wqobjT;
    wa.in[1] = Wo_obj; wa.out[1] = woobjT;
    wa.in[2] = Wq2;    wa.out[2] = wq2T;
    wa.in[3] = Wo2;    wa.out[3] = wo2T;
    wa.in[4] = laWq;   wa.out[4] = lawqT;
    wa.in[5] = laWk;   wa.out[5] = lawkT;
    wa.in[6] = laWv;   wa.out[6] = lawvT;
    wa.in[7] = laWo;   wa.out[7] = lawoT;
    transpose_w<<<dim3((8 * 320 * 320 + 255) / 256), 256, 0, stream>>>(wa, 320, 8);
    WB8 wb{};
    wb.in[0] = Wk_obj; wb.out[0] = wkobjT;
    wb.in[1] = Wv_obj; wb.out[1] = wvobjT;
    wb.in[2] = Wk2;    wb.out[2] = wk2T;
    wb.in[3] = Wv2;    wb.out[3] = wv2T;
    transpose_w<<<dim3((4 * 768 * 320 + 255) / 256), 256, 0, stream>>>(wb, 768, 4);

    resize_kernel<<<dim3(16), 256, 0, stream>>>(gmask, smask, sgv, gm_all, sig);
    posnet_kernel<<<dim3(4), 768, 0, stream>>>(box, pnW1, pnb1, pnW2, pnb2, pnW3, pnb3, boxtok);
    assemble_fg<<<dim3((4 * 336 * 768 + 255) / 256), 256, 0, stream>>>(ctx, imgf, boxtok, ctx_fg);
    assemble_bg<<<dim3((336 * 768 + 255) / 256), 256, 0, stream>>>(ctx, bgf, ctx_bg);
    ln_kernel<<<dim3(16384), 320, 0, stream>>>(itok + (size_t)4096 * 320, g_obj, b_obj, q_in);
    f2bf_kernel<<<dim3((4096 * 320 + 255) / 256), 256, 0, stream>>>(itok, x_la, 4096 * 320);

    // zero Vt pads so 0*NaN can't occur on first (pre-poison) call
    hipMemsetAsync(vt_obj, 0, (size_t)4 * 336 * 352 * 2, stream);
    hipMemsetAsync(vt_bg, 0, (size_t)336 * 352 * 2, stream);

    // K/V projections (ctx_fg: [1344][768], ctx_bg: [336][768])
    gemm320<0><<<dim3(21, 5), 256, 0, stream>>>(ctx_fg, wkobjT, nullptr, k_obj, nullptr, nullptr, nullptr, 1344, 768, 1, 0, 0);
    gemm320<1><<<dim3(21, 5), 256, 0, stream>>>(ctx_fg, wvobjT, nullptr, vt_obj, nullptr, nullptr, nullptr, 1344, 768, 336, (long)336 * 352, 352);
    gemm320<0><<<dim3(6, 5), 256, 0, stream>>>(ctx_bg, wk2T, nullptr, k_bg, nullptr, nullptr, nullptr, 336, 768, 1, 0, 0);
    gemm320<1><<<dim3(6, 5), 256, 0, stream>>>(ctx_bg, wv2T, nullptr, vt_bg, nullptr, nullptr, nullptr, 336, 768, 336, (long)336 * 352, 352);

    // ea_obj: Q-proj, attention, O-proj
    gemm320<0><<<dim3(256, 5), 256, 0, stream>>>(q_in, wqobjT, nullptr, q_obj, nullptr, nullptr, nullptr, 16384, 320, 1, 0, 0);
    flash_attn<352, false><<<dim3(64, 8, 4), 256, 0, stream>>>(q_obj, k_obj, vt_obj, o_obj, nullptr,
        335, (long)4096 * 320, (long)336 * 320, (long)336 * 352, 352);
    gemm320<2><<<dim3(256, 5), 256, 0, stream>>>(o_obj, woobjT, bo_obj, nullptr, ea, nullptr, nullptr, 16384, 320, 1, 0, 0);

    // S = sum_i sig*(ca_x[1+i]+ea_i); q2 = LN(S)
    s_ln_kernel<<<dim3(4096), 320, 0, stream>>>(ca_x, ea, sig, g2, b2, Sbuf, q2v);

    // ea2 (background)
    gemm320<0><<<dim3(64, 5), 256, 0, stream>>>(q2v, wq2T, nullptr, q2p, nullptr, nullptr, nullptr, 4096, 320, 1, 0, 0);
    flash_attn<352, false><<<dim3(64, 8, 1), 256, 0, stream>>>(q2p, k_bg, vt_bg, o2, nullptr,
        334, 0, 0, 0, 352);

    // layout self-attention with gm-mask
    gemm320<0><<<dim3(64, 5), 256, 0, stream>>>(x_la, lawqT, nullptr, ql, nullptr, nullptr, nullptr, 4096, 320, 1, 0, 0);
    gemm320<0><<<dim3(64, 5), 256, 0, stream>>>(x_la, lawkT, nullptr, kl, nullptr, nullptr, nullptr, 4096, 320, 1, 0, 0);
    gemm320<1><<<dim3(64, 5), 256, 0, stream>>>(x_la, lawvT, nullptr, vt_l, nullptr, nullptr, nullptr, 4096, 320, 4096, 0, 4096);
    flash_attn<256, true><<<dim3(64, 8, 1), 256, 0, stream>>>(ql, kl, vt_l, ol, gm_all,
        4096, 0, 0, 0, 4096);

    // out = ca_x[0] + S + ea_bg  (+ fusion)
    gemm320<3><<<dim3(64, 5), 256, 0, stream>>>(o2, wo2T, bo2, nullptr, (float*)d_out, ca_x, Sbuf, 4096, 320, 1, 0, 0);
    gemm320<4><<<dim3(64, 5), 256, 0, stream>>>(ol, lawoT, labo, nullptr, (float*)d_out, nullptr, nullptr, 4096, 320, 1, 0, 0);
}

// Round 2
// 663.756 us; speedup vs baseline: 1.1559x; 1.1559x over previous
//
#include <hip/hip_runtime.h>
#include <hip/hip_bf16.h>
#include <math.h>

typedef unsigned short bhalf;
typedef unsigned int u32;
typedef unsigned long long u64;
typedef __attribute__((ext_vector_type(8))) short s16x8;
typedef __attribute__((ext_vector_type(4))) float f32x4;

#define SCALE_QK 0.15811388300841898f
#define K2E (SCALE_QK * 1.4426950408889634f)
#define NEG_INF (-3.402823466e38f)

__device__ __forceinline__ float bf2f(bhalf u){
    union { unsigned int i; float f; } v; v.i = ((unsigned int)u) << 16; return v.f;
}
__device__ __forceinline__ bhalf f2bf(float f){
    unsigned int x = __float_as_uint(f);
    unsigned int r = (x + 0x7fffu + ((x >> 16) & 1u)) >> 16;
    return (bhalf)r;
}
__device__ __forceinline__ float fexp2(float x){
    float r; asm("v_exp_f32 %0, %1" : "=v"(r) : "v"(x)); return r;
}
__device__ __forceinline__ u32 cvtpk(float lo, float hi){
    u32 r; asm("v_cvt_pk_bf16_f32 %0, %1, %2" : "=v"(r) : "v"(lo), "v"(hi)); return r;
}

// ---------------------------------------------------------------- weight prep
struct WB8 { const float* in[8]; bhalf* out[8]; };

__global__ void transpose_w(WB8 wb, int K, int cnt){
    const int per = 320 * K;
    for (int idx = blockIdx.x * 256 + threadIdx.x; idx < cnt * per; idx += gridDim.x * 256){
        const int w = idx / per, rem = idx % per;
        const int n = rem / K, k = rem % K;
        wb.out[w][rem] = f2bf(wb.in[w][(long)k * 320 + n]);
    }
}

// ---------------------------------------------------------------- resize (8x down, half-pixel bilinear -> 4-tap avg)
__global__ void resize_kernel(const float* __restrict__ gm, const float* __restrict__ supp,
                              const float* __restrict__ sgv, float* __restrict__ gm_all,
                              float* __restrict__ sig){
    const int i = blockIdx.x * 256 + threadIdx.x;
    if (i >= 4096) return;
    const int y = i >> 6, x = i & 63;
    const int o = (8 * y + 3) * 512 + 8 * x + 3;
#pragma unroll
    for (int p = 0; p < 4; ++p){
        const float* s = gm + (long)p * 262144;
        gm_all[p * 4096 + i] = 0.25f * (s[o] + s[o + 1] + s[o + 512] + s[o + 513]);
    }
    gm_all[4 * 4096 + i] = 0.25f * (supp[o] + supp[o + 1] + supp[o + 512] + supp[o + 513]);
#pragma unroll
    for (int p = 0; p < 4; ++p){
        const float* s = sgv + (long)p * 262144;
        sig[p * 4096 + i] = 0.25f * (s[o] + s[o + 1] + s[o + 512] + s[o + 513]);
    }
}

// ---------------------------------------------------------------- guidance-mask bitmap: bit(i,j) = dot5(gm[:,i],gm[:,j]) != 0
// grid (64, 4): block = rows i0..i0+63 x words (j0/64)..(j0/64+15). Wave-uniform gj reads (broadcast, 0 conflicts).
__global__ __launch_bounds__(256) void maskbits_kernel(const float* __restrict__ gm_all, u64* __restrict__ mb){
    __shared__ float gi[5][64];
    __shared__ float gj[5][1024];
    const int t = threadIdx.x;
    const int i0 = blockIdx.x << 6, j0 = blockIdx.y << 10;
    for (int idx = t; idx < 5 * 64; idx += 256)
        gi[idx >> 6][idx & 63] = gm_all[(idx >> 6) * 4096 + i0 + (idx & 63)];
    for (int idx = t; idx < 5 * 1024; idx += 256)
        gj[idx >> 10][idx & 1023] = gm_all[(idx >> 10) * 4096 + j0 + (idx & 1023)];
    __syncthreads();
    const int lane = t & 63, wave = t >> 6;
    const float a0 = gi[0][lane], a1 = gi[1][lane], a2 = gi[2][lane], a3 = gi[3][lane], a4 = gi[4][lane];
    for (int ww = wave; ww < 16; ww += 4){
        u64 m = 0;
        for (int j = 0; j < 64; ++j){
            const int jj = (ww << 6) + j;
            const float dot = a0 * gj[0][jj] + a1 * gj[1][jj] + a2 * gj[2][jj]
                            + a3 * gj[3][jj] + a4 * gj[4][jj];
            m |= (u64)(dot != 0.f) << j;
        }
        mb[(long)(i0 + lane) * 64 + (j0 >> 6) + ww] = m;
    }
}

// ---------------------------------------------------------------- PositionNet (fourier + 3-layer MLP), one block per box
__global__ __launch_bounds__(768) void posnet_kernel(
    const float* __restrict__ box,
    const float* __restrict__ W1, const float* __restrict__ b1,
    const float* __restrict__ W2, const float* __restrict__ b2,
    const float* __restrict__ W3, const float* __restrict__ b3,
    float* __restrict__ tok)
{
    const int bb = blockIdx.x, t = threadIdx.x;
    __shared__ float emb[128], h1[512], h2[512];
    if (t < 128){
        const int i = t >> 4, jj = t & 15, j = jj & 7;
        const float f = powf(100.f, (float)i * 0.125f);
        const float v = f * box[bb * 8 + j];
        emb[t] = (jj < 8) ? sinf(v) : cosf(v);
    }
    __syncthreads();
    if (t < 512){
        float a = b1[t];
        for (int k = 0; k < 128; ++k) a += emb[k] * W1[k * 512 + t];
        h1[t] = a / (1.f + __expf(-a));
    }
    __syncthreads();
    if (t < 512){
        float a = b2[t];
        for (int k = 0; k < 512; ++k) a += h1[k] * W2[k * 512 + t];
        h2[t] = a / (1.f + __expf(-a));
    }
    __syncthreads();
    {
        float a = b3[t];
        for (int k = 0; k < 512; ++k) a += h2[k] * W3[k * 768 + t];
        tok[bb * 768 + t] = a;
    }
}

// ---------------------------------------------------------------- context assembly (f32 -> bf16)
__global__ void assemble_fg(const float* __restrict__ context, const float* __restrict__ imgf,
                            const float* __restrict__ boxtok, bhalf* __restrict__ out){
    const int idx = blockIdx.x * 256 + threadIdx.x;
    if (idx >= 4 * 336 * 768) return;
    const int i = idx / (336 * 768);
    const int r = (idx / 768) % 336;
    const int c = idx % 768;
    float v;
    if (r < 77)       v = context[((long)(1 + i) * 77 + r) * 768 + c];
    else if (r < 334) v = imgf[((long)i * 257 + (r - 77)) * 768 + c];
    else if (r == 334) v = boxtok[i * 768 + c];
    else v = 0.f;
    out[idx] = f2bf(v);
}
__global__ void assemble_bg(const float* __restrict__ context, const float* __restrict__ bgf,
                            bhalf* __restrict__ out){
    const int idx = blockIdx.x * 256 + threadIdx.x;
    if (idx >= 336 * 768) return;
    const int r = idx / 768, c = idx % 768;
    float v;
    if (r < 77)       v = context[(long)r * 768 + c];
    else if (r < 334) v = bgf[(long)(r - 77) * 768 + c];
    else v = 0.f;
    out[idx] = f2bf(v);
}

// ---------------------------------------------------------------- LayerNorm over C=320, one block per row
__global__ __launch_bounds__(320) void ln_kernel(
    const float* __restrict__ in, const float* __restrict__ g, const float* __restrict__ b,
    bhalf* __restrict__ out)
{
    const int row = blockIdx.x, c = threadIdx.x;
    const float v = in[(long)row * 320 + c];
    float s = v, sq = v * v;
#pragma unroll
    for (int o = 1; o < 64; o <<= 1){ s += __shfl_xor(s, o); sq += __shfl_xor(sq, o); }
    __shared__ float rs[5], rq[5];
    const int wv = threadIdx.x >> 6;
    if ((threadIdx.x & 63) == 0){ rs[wv] = s; rq[wv] = sq; }
    __syncthreads();
    if (threadIdx.x == 0){
        float ts = 0, tq = 0;
#pragma unroll
        for (int w = 0; w < 5; ++w){ ts += rs[w]; tq += rq[w]; }
        rs[0] = ts; rq[0] = tq;
    }
    __syncthreads();
    const float mean = rs[0] * (1.f / 320.f);
    const float var  = rq[0] * (1.f / 320.f) - mean * mean;
    const float inv  = rsqrtf(var + 1e-5f);
    out[(long)row * 320 + c] = f2bf((v - mean) * inv * g[c] + b[c]);
}

// S = sum_i sig_i * (ca_x[1+i] + ea_i), then q2 = LN(S)
__global__ __launch_bounds__(320) void s_ln_kernel(
    const float* __restrict__ ca_x, const float* __restrict__ ea, const float* __restrict__ sig,
    const float* __restrict__ g, const float* __restrict__ b,
    float* __restrict__ S, bhalf* __restrict__ q2)
{
    const int hw = blockIdx.x, c = threadIdx.x;
    float v = 0.f;
#pragma unroll
    for (int i = 0; i < 4; ++i){
        const float sg = sig[i * 4096 + hw];
        v += sg * (ca_x[((long)(1 + i) * 4096 + hw) * 320 + c] + ea[((long)i * 4096 + hw) * 320 + c]);
    }
    S[(long)hw * 320 + c] = v;
    float s = v, sq = v * v;
#pragma unroll
    for (int o = 1; o < 64; o <<= 1){ s += __shfl_xor(s, o); sq += __shfl_xor(sq, o); }
    __shared__ float rs[5], rq[5];
    const int wv = threadIdx.x >> 6;
    if ((threadIdx.x & 63) == 0){ rs[wv] = s; rq[wv] = sq; }
    __syncthreads();
    if (threadIdx.x == 0){
        float ts = 0, tq = 0;
#pragma unroll
        for (int w = 0; w < 5; ++w){ ts += rs[w]; tq += rq[w]; }
        rs[0] = ts; rq[0] = tq;
    }
    __syncthreads();
    const float mean = rs[0] * (1.f / 320.f);
    const float var  = rq[0] * (1.f / 320.f) - mean * mean;
    const float inv  = rsqrtf(var + 1e-5f);
    q2[(long)hw * 320 + c] = f2bf((v - mean) * inv * g[c] + b[c]);
}

__global__ void f2bf_kernel(const float* __restrict__ in, bhalf* __restrict__ out, int n){
    const int i = blockIdx.x * 256 + threadIdx.x;
    if (i < n) out[i] = f2bf(in[i]);
}

// ---------------------------------------------------------------- generic GEMM: C[M][320] = A[M][K] @ Wt[320][K]^T
template<int MODE>
__global__ __launch_bounds__(256) void gemm320(
    const bhalf* __restrict__ A, const bhalf* __restrict__ Wt,
    const float* __restrict__ bias, bhalf* __restrict__ Cbf,
    float* __restrict__ Cf, const float* __restrict__ add1, const float* __restrict__ add2,
    int M, int K, int vt_mod, long vt_istride, int vt_cstride)
{
    const int wave = threadIdx.x >> 6, lane = threadIdx.x & 63;
    const int m0 = blockIdx.x * 64 + wave * 16;
    const int n0 = blockIdx.y * 64;
    int mrow = m0 + (lane & 15); if (mrow > M - 1) mrow = M - 1;
    const int klo = (lane >> 4) * 8;
    const bhalf* ap = A + (long)mrow * K + klo;
    const bhalf* wp = Wt + (long)(n0 + (lane & 15)) * K + klo;
    const f32x4 fz = {0.f, 0.f, 0.f, 0.f};
    f32x4 acc[4]; acc[0] = fz; acc[1] = fz; acc[2] = fz; acc[3] = fz;
    for (int k0 = 0; k0 < K; k0 += 32){
        s16x8 a = *(const s16x8*)(ap + k0);
#pragma unroll
        for (int t = 0; t < 4; ++t){
            s16x8 b = *(const s16x8*)(wp + (long)t * 16 * K + k0);
            acc[t] = __builtin_amdgcn_mfma_f32_16x16x32_bf16(a, b, acc[t], 0, 0, 0);
        }
    }
    const int rb = m0 + (lane >> 4) * 4;
#pragma unroll
    for (int t = 0; t < 4; ++t){
        const int col = n0 + t * 16 + (lane & 15);
#pragma unroll
        for (int r = 0; r < 4; ++r){
            const int row = rb + r;
            if (row >= M) continue;
            const float v = acc[t][r];
            if (MODE == 0) Cbf[(long)row * 320 + col] = f2bf(v);
            else if (MODE == 1) Cbf[(long)(row / vt_mod) * vt_istride + (long)col * vt_cstride + (row % vt_mod)] = f2bf(v);
            else if (MODE == 2) Cf[(long)row * 320 + col] = v + bias[col];
            else if (MODE == 3){ const long o = (long)row * 320 + col; Cf[o] = v + bias[col] + add1[o] + add2[o]; }
            else { const long o = (long)row * 320 + col; Cf[o] += v + bias[col]; }
        }
    }
}

// ---------------------------------------------------------------- flash attention v2: register softmax, no LDS, no barriers
// Swapped QK^T (mfma(K,Q)) with permuted K-row feeding so each lane's scores land exactly on its PV
// B-fragment kv-slice. Swapped PV (mfma(Vt,P)). All softmax state lane-local in q = lane&15.
// Each wave: 16 q-rows, chunks of 64 kv. GMM: u64 mask word per (q, chunk), wave-uniform all-keep fast path.
template<bool GMM>
__global__ __launch_bounds__(256) void flash2(
    const bhalf* __restrict__ Q, const bhalf* __restrict__ Kc, const bhalf* __restrict__ Vt,
    bhalf* __restrict__ O, const u64* __restrict__ maskb,
    int NKV, long q_is, long k_is, long vt_is, int vt_ns)
{
    const int lane = threadIdx.x & 63, wave = threadIdx.x >> 6;
    const int l15 = lane & 15, hi = lane >> 4, klo = hi * 8;
    const int h = blockIdx.y, inst = blockIdx.z;
    const int q = blockIdx.x * 64 + wave * 16 + l15;
    const s16x8 z8 = {0, 0, 0, 0, 0, 0, 0, 0};
    const f32x4 fz = {0.f, 0.f, 0.f, 0.f};

    // Q as B-operand: col = l15 = q, k = klo + j
    const bhalf* qp = Q + inst * q_is + (long)q * 320 + h * 40;
    const s16x8 qb0 = *(const s16x8*)(qp + klo);
    const s16x8 qb1 = (hi == 0) ? *(const s16x8*)(qp + 32) : z8;

    // permuted K row base: tile t reads kv = c0 + 32*(t>>1) + 4*(t&1) + krbase
    const int krbase = 8 * (l15 >> 2) + (l15 & 3);
    const bhalf* kbase = Kc + inst * k_is + h * 40 + (long)krbase * 320;

    // V row pointers (A-operand rows = d-channel, clamped to 319), col offset 8*hi
    const bhalf* vbase[3];
#pragma unroll
    for (int ct = 0; ct < 3; ++ct){
        int dr = h * 40 + ct * 16 + l15; if (dr > 319) dr = 319;
        vbase[ct] = Vt + inst * vt_is + (long)dr * vt_ns + hi * 8;
    }

    f32x4 acc[3]; acc[0] = fz; acc[1] = fz; acc[2] = fz;
    float m_run = NEG_INF, l_run = 0.f;

    auto soft_pv = [&](f32x4 (&d)[4], int c0){
        float cmax = NEG_INF;
#pragma unroll
        for (int t = 0; t < 4; ++t)
#pragma unroll
            for (int r = 0; r < 4; ++r) cmax = fmaxf(cmax, d[t][r]);
        cmax = fmaxf(cmax, __shfl_xor(cmax, 16));
        cmax = fmaxf(cmax, __shfl_xor(cmax, 32));
        const float mnew = fmaxf(m_run, cmax);
        const float fac = fexp2((m_run - mnew) * K2E);
        const float negm = -mnew * K2E;
        float csum = 0.f;
#pragma unroll
        for (int t = 0; t < 4; ++t)
#pragma unroll
            for (int r = 0; r < 4; ++r){
                const float p = fexp2(fmaf(d[t][r], K2E, negm));
                d[t][r] = p; csum += p;
            }
        csum += __shfl_xor(csum, 16);
        csum += __shfl_xor(csum, 32);
        l_run = l_run * fac + csum;
        m_run = mnew;
#pragma unroll
        for (int ct = 0; ct < 3; ++ct)
#pragma unroll
            for (int r = 0; r < 4; ++r) acc[ct][r] *= fac;
#pragma unroll
        for (int s = 0; s < 2; ++s){
            union { u32 w[4]; s16x8 v; } pb;
            pb.w[0] = cvtpk(d[2 * s][0], d[2 * s][1]);
            pb.w[1] = cvtpk(d[2 * s][2], d[2 * s][3]);
            pb.w[2] = cvtpk(d[2 * s + 1][0], d[2 * s + 1][1]);
            pb.w[3] = cvtpk(d[2 * s + 1][2], d[2 * s + 1][3]);
#pragma unroll
            for (int ct = 0; ct < 3; ++ct){
                const s16x8 va = *(const s16x8*)(vbase[ct] + c0 + 32 * s);
                acc[ct] = __builtin_amdgcn_mfma_f32_16x16x32_bf16(va, pb.v, acc[ct], 0, 0, 0);
            }
        }
    };

    const int nfull = NKV >> 6;
    for (int ch = 0; ch < nfull; ++ch){
        const int c0 = ch << 6;
        u64 M = ~0ull;
        if (GMM){
            M = maskb[(long)q * 64 + ch];
            if (__all(M == 0)) continue;
        }
        f32x4 d[4];
#pragma unroll
        for (int t = 0; t < 4; ++t){
            const int toff = ((t >> 1) << 5) + ((t & 1) << 2);
            const bhalf* kp = kbase + (long)(c0 + toff) * 320;
            const s16x8 k0 = *(const s16x8*)(kp + klo);
            const s16x8 k1 = (hi == 0) ? *(const s16x8*)(kp + 32) : z8;
            d[t] = __builtin_amdgcn_mfma_f32_16x16x32_bf16(k0, qb0, fz, 0, 0, 0);
            d[t] = __builtin_amdgcn_mfma_f32_16x16x32_bf16(k1, qb1, d[t], 0, 0, 0);
        }
        if (GMM && !__all(M == ~0ull)){
            const u64 Mh = M >> (hi * 8);
#pragma unroll
            for (int t = 0; t < 4; ++t){
                const int tb = ((t >> 1) << 5) + ((t & 1) << 2);
#pragma unroll
                for (int r = 0; r < 4; ++r)
                    if (!((Mh >> (tb + r)) & 1)) d[t][r] = NEG_INF;
            }
        }
        soft_pv(d, c0);
    }
    if (NKV & 63){
        const int c0 = nfull << 6;
        f32x4 d[4];
#pragma unroll
        for (int t = 0; t < 4; ++t){
            const int toff = ((t >> 1) << 5) + ((t & 1) << 2);
            int kr = c0 + toff + krbase; if (kr > NKV - 1) kr = NKV - 1;
            const bhalf* kp = Kc + inst * k_is + h * 40 + (long)kr * 320;
            const s16x8 k0 = *(const s16x8*)(kp + klo);
            const s16x8 k1 = (hi == 0) ? *(const s16x8*)(kp + 32) : z8;
            d[t] = __builtin_amdgcn_mfma_f32_16x16x32_bf16(k0, qb0, fz, 0, 0, 0);
            d[t] = __builtin_amdgcn_mfma_f32_16x16x32_bf16(k1, qb1, d[t], 0, 0, 0);
        }
#pragma unroll
        for (int t = 0; t < 4; ++t){
            const int tb = ((t >> 1) << 5) + ((t & 1) << 2);
#pragma unroll
            for (int r = 0; r < 4; ++r)
                if (c0 + tb + hi * 8 + r >= NKV) d[t][r] = NEG_INF;
        }
        soft_pv(d, c0);
    }

    // write: lane-local q, d = ct*16 + 4*hi + r
    const float inv = 1.f / l_run;
    bhalf* op = O + inst * q_is + (long)q * 320 + h * 40;
#pragma unroll
    for (int ct = 0; ct < 3; ++ct){
        const int d0 = ct * 16 + hi * 4;
        if (d0 < 40){
            uint2 w;
            w.x = cvtpk(acc[ct][0] * inv, acc[ct][1] * inv);
            w.y = cvtpk(acc[ct][2] * inv, acc[ct][3] * inv);
            *(uint2*)(op + d0) = w;
        }
    }
}

// ================================================================ host
extern "C" void kernel_launch(void* const* d_in, const int* in_sizes, int n_in,
                              void* d_out, int out_size, void* d_ws, size_t ws_size,
                              hipStream_t stream)
{
    (void)in_sizes; (void)n_in; (void)out_size; (void)ws_size;
    const float* ca_x   = (const float*)d_in[0];
    const float* gmask  = (const float*)d_in[1];
    const float* smask  = (const float*)d_in[2];
    const float* itok   = (const float*)d_in[3];
    const float* ctx    = (const float*)d_in[4];
    const float* box    = (const float*)d_in[5];
    const float* imgf   = (const float*)d_in[6];
    const float* bgf    = (const float*)d_in[7];
    const float* sgv    = (const float*)d_in[8];
    const float* Wq_obj = (const float*)d_in[9];
    const float* Wk_obj = (const float*)d_in[10];
    const float* Wv_obj = (const float*)d_in[11];
    const float* Wo_obj = (const float*)d_in[12];
    const float* bo_obj = (const float*)d_in[13];
    const float* g_obj  = (const float*)d_in[14];
    const float* b_obj  = (const float*)d_in[15];
    const float* Wq2    = (const float*)d_in[16];
    const float* Wk2    = (const float*)d_in[17];
    const float* Wv2    = (const float*)d_in[18];
    const float* Wo2    = (const float*)d_in[19];
    const float* bo2    = (const float*)d_in[20];
    const float* g2     = (const float*)d_in[21];
    const float* b2     = (const float*)d_in[22];
    const float* pnW1   = (const float*)d_in[23];
    const float* pnb1   = (const float*)d_in[24];
    const float* pnW2   = (const float*)d_in[25];
    const float* pnb2   = (const float*)d_in[26];
    const float* pnW3   = (const float*)d_in[27];
    const float* pnb3   = (const float*)d_in[28];
    const float* laWq   = (const float*)d_in[29];
    const float* laWk   = (const float*)d_in[30];
    const float* laWv   = (const float*)d_in[31];
    const float* laWo   = (const float*)d_in[32];
    const float* labo   = (const float*)d_in[33];

    char* wsp = (char*)d_ws; size_t off = 0;
    auto alloc = [&](size_t bytes) -> void* {
        void* p = wsp + off; off += (bytes + 255) & ~(size_t)255; return p;
    };
    bhalf* wqobjT = (bhalf*)alloc(320 * 320 * 2);
    bhalf* woobjT = (bhalf*)alloc(320 * 320 * 2);
    bhalf* wq2T   = (bhalf*)alloc(320 * 320 * 2);
    bhalf* wo2T   = (bhalf*)alloc(320 * 320 * 2);
    bhalf* lawqT  = (bhalf*)alloc(320 * 320 * 2);
    bhalf* lawkT  = (bhalf*)alloc(320 * 320 * 2);
    bhalf* lawvT  = (bhalf*)alloc(320 * 320 * 2);
    bhalf* lawoT  = (bhalf*)alloc(320 * 320 * 2);
    bhalf* wkobjT = (bhalf*)alloc(768 * 320 * 2);
    bhalf* wvobjT = (bhalf*)alloc(768 * 320 * 2);
    bhalf* wk2T   = (bhalf*)alloc(768 * 320 * 2);
    bhalf* wv2T   = (bhalf*)alloc(768 * 320 * 2);
    float* gm_all = (float*)alloc(5 * 4096 * 4);
    float* sig    = (float*)alloc(4 * 4096 * 4);
    float* boxtok = (float*)alloc(4 * 768 * 4);
    u64*   maskb  = (u64*)alloc((size_t)4096 * 64 * 8);
    bhalf* ctx_fg = (bhalf*)alloc((size_t)4 * 336 * 768 * 2);
    bhalf* ctx_bg = (bhalf*)alloc((size_t)336 * 768 * 2);
    bhalf* q_in   = (bhalf*)alloc((size_t)16384 * 320 * 2);
    bhalf* x_la   = (bhalf*)alloc((size_t)4096 * 320 * 2);
    bhalf* k_obj  = (bhalf*)alloc((size_t)4 * 336 * 320 * 2);
    bhalf* vt_obj = (bhalf*)alloc((size_t)4 * 320 * 384 * 2);
    bhalf* k_bg   = (bhalf*)alloc((size_t)336 * 320 * 2);
    bhalf* vt_bg  = (bhalf*)alloc((size_t)320 * 384 * 2);
    bhalf* q_obj  = (bhalf*)alloc((size_t)16384 * 320 * 2);
    bhalf* o_obj  = (bhalf*)alloc((size_t)16384 * 320 * 2);
    float* ea     = (float*)alloc((size_t)16384 * 320 * 4);
    float* Sbuf   = (float*)alloc((size_t)4096 * 320 * 4);
    bhalf* q2v    = (bhalf*)alloc((size_t)4096 * 320 * 2);
    bhalf* q2p    = (bhalf*)alloc((size_t)4096 * 320 * 2);
    bhalf* o2     = (bhalf*)alloc((size_t)4096 * 320 * 2);
    bhalf* ql     = (bhalf*)alloc((size_t)4096 * 320 * 2);
    bhalf* kl     = (bhalf*)alloc((size_t)4096 * 320 * 2);
    bhalf* vt_l   = (bhalf*)alloc((size_t)320 * 4096 * 2);
    bhalf* ol     = (bhalf*)alloc((size_t)4096 * 320 * 2);

    // weight transposes (bf16, [N][K])
    WB8 wa{};
    wa.in[0] = Wq_obj; wa.out[0] = wqobjT;
    wa.in[1] = Wo_obj; wa.out[1] = woobjT;
    wa.in[2] = Wq2;    wa.out[2] = wq2T;
    wa.in[3] = Wo2;    wa.out[3] = wo2T;
    wa.in[4] = laWq;   wa.out[4] = lawqT;
    wa.in[5] = laWk;   wa.out[5] = lawkT;
    wa.in[6] = laWv;   wa.out[6] = lawvT;
    wa.in[7] = laWo;   wa.out[7] = lawoT;
    transpose_w<<<dim3((8 * 320 * 320 + 255) / 256), 256, 0, stream>>>(wa, 320, 8);
    WB8 wb{};
    wb.in[0] = Wk_obj; wb.out[0] = wkobjT;
    wb.in[1] = Wv_obj; wb.out[1] = wvobjT;
    wb.in[2] = Wk2;    wb.out[2] = wk2T;
    wb.in[3] = Wv2;    wb.out[3] = wv2T;
    transpose_w<<<dim3((4 * 768 * 320 + 255) / 256), 256, 0, stream>>>(wb, 768, 4);

    resize_kernel<<<dim3(16), 256, 0, stream>>>(gmask, smask, sgv, gm_all, sig);
    maskbits_kernel<<<dim3(64, 4), 256, 0, stream>>>(gm_all, maskb);
    posnet_kernel<<<dim3(4), 768, 0, stream>>>(box, pnW1, pnb1, pnW2, pnb2, pnW3, pnb3, boxtok);
    assemble_fg<<<dim3((4 * 336 * 768 + 255) / 256), 256, 0, stream>>>(ctx, imgf, boxtok, ctx_fg);
    assemble_bg<<<dim3((336 * 768 + 255) / 256), 256, 0, stream>>>(ctx, bgf, ctx_bg);
    ln_kernel<<<dim3(16384), 320, 0, stream>>>(itok + (size_t)4096 * 320, g_obj, b_obj, q_in);
    f2bf_kernel<<<dim3((4096 * 320 + 255) / 256), 256, 0, stream>>>(itok, x_la, 4096 * 320);

    // zero Vt pad columns (cols NKV..383) so P=0 x pad is exact
    hipMemsetAsync(vt_obj, 0, (size_t)4 * 320 * 384 * 2, stream);
    hipMemsetAsync(vt_bg, 0, (size_t)320 * 384 * 2, stream);

    // K/V projections (ctx_fg: [1344][768], ctx_bg: [336][768])
    gemm320<0><<<dim3(21, 5), 256, 0, stream>>>(ctx_fg, wkobjT, nullptr, k_obj, nullptr, nullptr, nullptr, 1344, 768, 1, 0, 0);
    gemm320<1><<<dim3(21, 5), 256, 0, stream>>>(ctx_fg, wvobjT, nullptr, vt_obj, nullptr, nullptr, nullptr, 1344, 768, 336, (long)320 * 384, 384);
    gemm320<0><<<dim3(6, 5), 256, 0, stream>>>(ctx_bg, wk2T, nullptr, k_bg, nullptr, nullptr, nullptr, 336, 768, 1, 0, 0);
    gemm320<1><<<dim3(6, 5), 256, 0, stream>>>(ctx_bg, wv2T, nullptr, vt_bg, nullptr, nullptr, nullptr, 336, 768, 336, 0, 384);

    // ea_obj: Q-proj, attention, O-proj
    gemm320<0><<<dim3(256, 5), 256, 0, stream>>>(q_in, wqobjT, nullptr, q_obj, nullptr, nullptr, nullptr, 16384, 320, 1, 0, 0);
    flash2<false><<<dim3(64, 8, 4), 256, 0, stream>>>(q_obj, k_obj, vt_obj, o_obj, nullptr,
        335, (long)4096 * 320, (long)336 * 320, (long)320 * 384, 384);
    gemm320<2><<<dim3(256, 5), 256, 0, stream>>>(o_obj, woobjT, bo_obj, nullptr, ea, nullptr, nullptr, 16384, 320, 1, 0, 0);

    // S = sum_i sig*(ca_x[1+i]+ea_i); q2 = LN(S)
    s_ln_kernel<<<dim3(4096), 320, 0, stream>>>(ca_x, ea, sig, g2, b2, Sbuf, q2v);

    // ea2 (background)
    gemm320<0><<<dim3(64, 5), 256, 0, stream>>>(q2v, wq2T, nullptr, q2p, nullptr, nullptr, nullptr, 4096, 320, 1, 0, 0);
    flash2<false><<<dim3(64, 8, 1), 256, 0, stream>>>(q2p, k_bg, vt_bg, o2, nullptr,
        334, 0, 0, 0, 384);

    // layout self-attention with gm-mask
    gemm320<0><<<dim3(64, 5), 256, 0, stream>>>(x_la, lawqT, nullptr, ql, nullptr, nullptr, nullptr, 4096, 320, 1, 0, 0);
    gemm320<0><<<dim3(64, 5), 256, 0, stream>>>(x_la, lawkT, nullptr, kl, nullptr, nullptr, nullptr, 4096, 320, 1, 0, 0);
    gemm320<1><<<dim3(64, 5), 256, 0, stream>>>(x_la, lawvT, nullptr, vt_l, nullptr, nullptr, nullptr, 4096, 320, 4096, 0, 4096);
    flash2<true><<<dim3(64, 8, 1), 256, 0, stream>>>(ql, kl, vt_l, ol, maskb,
        4096, 0, 0, 0, 4096);

    // out = ca_x[0] + S + ea_bg  (+ fusion)
    gemm320<3><<<dim3(64, 5), 256, 0, stream>>>(o2, wo2T, bo2, nullptr, (float*)d_out, ca_x, Sbuf, 4096, 320, 1, 0, 0);
    gemm320<4><<<dim3(64, 5), 256, 0, stream>>>(ol, lawoT, labo, nullptr, (float*)d_out, nullptr, nullptr, 4096, 320, 1, 0, 0);
}

// Round 3
// 649.231 us; speedup vs baseline: 1.1818x; 1.0224x over previous
//
#include <hip/hip_runtime.h>
#include <hip/hip_bf16.h>
#include <math.h>

typedef unsigned short bhalf;
typedef unsigned int u32;
typedef unsigned long long u64;
typedef __attribute__((ext_vector_type(8))) short s16x8;
typedef __attribute__((ext_vector_type(4))) float f32x4;

#define SCALE_QK 0.15811388300841898f
#define K2E (SCALE_QK * 1.4426950408889634f)
#define NEG_INF (-3.402823466e38f)

__device__ __forceinline__ float bf2f(bhalf u){
    union { unsigned int i; float f; } v; v.i = ((unsigned int)u) << 16; return v.f;
}
__device__ __forceinline__ bhalf f2bf(float f){
    unsigned int x = __float_as_uint(f);
    unsigned int r = (x + 0x7fffu + ((x >> 16) & 1u)) >> 16;
    return (bhalf)r;
}
__device__ __forceinline__ float fexp2(float x){
    float r; asm("v_exp_f32 %0, %1" : "=v"(r) : "v"(x)); return r;
}
__device__ __forceinline__ u32 cvtpk(float lo, float hi){
    u32 r; asm("v_cvt_pk_bf16_f32 %0, %1, %2" : "=v"(r) : "v"(lo), "v"(hi)); return r;
}

// ---------------------------------------------------------------- weight prep
struct WB8 { const float* in[8]; bhalf* out[8]; };

__global__ void transpose_w(WB8 wb, int K, int cnt){
    const int per = 320 * K;
    for (int idx = blockIdx.x * 256 + threadIdx.x; idx < cnt * per; idx += gridDim.x * 256){
        const int w = idx / per, rem = idx % per;
        const int n = rem / K, k = rem % K;
        wb.out[w][rem] = f2bf(wb.in[w][(long)k * 320 + n]);
    }
}

// ---------------------------------------------------------------- resize (8x down, half-pixel bilinear -> 4-tap avg)
__global__ void resize_kernel(const float* __restrict__ gm, const float* __restrict__ supp,
                              const float* __restrict__ sgv, float* __restrict__ gm_all,
                              float* __restrict__ sig){
    const int i = blockIdx.x * 256 + threadIdx.x;
    if (i >= 4096) return;
    const int y = i >> 6, x = i & 63;
    const int o = (8 * y + 3) * 512 + 8 * x + 3;
#pragma unroll
    for (int p = 0; p < 4; ++p){
        const float* s = gm + (long)p * 262144;
        gm_all[p * 4096 + i] = 0.25f * (s[o] + s[o + 1] + s[o + 512] + s[o + 513]);
    }
    gm_all[4 * 4096 + i] = 0.25f * (supp[o] + supp[o + 1] + supp[o + 512] + supp[o + 513]);
#pragma unroll
    for (int p = 0; p < 4; ++p){
        const float* s = sgv + (long)p * 262144;
        sig[p * 4096 + i] = 0.25f * (s[o] + s[o + 1] + s[o + 512] + s[o + 513]);
    }
}

// ---------------------------------------------------------------- guidance-mask bitmap
__global__ __launch_bounds__(256) void maskbits_kernel(const float* __restrict__ gm_all, u64* __restrict__ mb){
    __shared__ float gi[5][64];
    __shared__ float gj[5][1024];
    const int t = threadIdx.x;
    const int i0 = blockIdx.x << 6, j0 = blockIdx.y << 10;
    for (int idx = t; idx < 5 * 64; idx += 256)
        gi[idx >> 6][idx & 63] = gm_all[(idx >> 6) * 4096 + i0 + (idx & 63)];
    for (int idx = t; idx < 5 * 1024; idx += 256)
        gj[idx >> 10][idx & 1023] = gm_all[(idx >> 10) * 4096 + j0 + (idx & 1023)];
    __syncthreads();
    const int lane = t & 63, wave = t >> 6;
    const float a0 = gi[0][lane], a1 = gi[1][lane], a2 = gi[2][lane], a3 = gi[3][lane], a4 = gi[4][lane];
    for (int ww = wave; ww < 16; ww += 4){
        u64 m = 0;
        for (int j = 0; j < 64; ++j){
            const int jj = (ww << 6) + j;
            const float dot = a0 * gj[0][jj] + a1 * gj[1][jj] + a2 * gj[2][jj]
                            + a3 * gj[3][jj] + a4 * gj[4][jj];
            m |= (u64)(dot != 0.f) << j;
        }
        mb[(long)(i0 + lane) * 64 + (j0 >> 6) + ww] = m;
    }
}

// ---------------------------------------------------------------- PositionNet
__global__ __launch_bounds__(768) void posnet_kernel(
    const float* __restrict__ box,
    const float* __restrict__ W1, const float* __restrict__ b1,
    const float* __restrict__ W2, const float* __restrict__ b2,
    const float* __restrict__ W3, const float* __restrict__ b3,
    float* __restrict__ tok)
{
    const int bb = blockIdx.x, t = threadIdx.x;
    __shared__ float emb[128], h1[512], h2[512];
    if (t < 128){
        const int i = t >> 4, jj = t & 15, j = jj & 7;
        const float f = powf(100.f, (float)i * 0.125f);
        const float v = f * box[bb * 8 + j];
        emb[t] = (jj < 8) ? sinf(v) : cosf(v);
    }
    __syncthreads();
    if (t < 512){
        float a = b1[t];
        for (int k = 0; k < 128; ++k) a += emb[k] * W1[k * 512 + t];
        h1[t] = a / (1.f + __expf(-a));
    }
    __syncthreads();
    if (t < 512){
        float a = b2[t];
        for (int k = 0; k < 512; ++k) a += h1[k] * W2[k * 512 + t];
        h2[t] = a / (1.f + __expf(-a));
    }
    __syncthreads();
    {
        float a = b3[t];
        for (int k = 0; k < 512; ++k) a += h2[k] * W3[k * 768 + t];
        tok[bb * 768 + t] = a;
    }
}

// ---------------------------------------------------------------- context assembly (f32 -> bf16)
__global__ void assemble_fg(const float* __restrict__ context, const float* __restrict__ imgf,
                            const float* __restrict__ boxtok, bhalf* __restrict__ out){
    const int idx = blockIdx.x * 256 + threadIdx.x;
    if (idx >= 4 * 336 * 768) return;
    const int i = idx / (336 * 768);
    const int r = (idx / 768) % 336;
    const int c = idx % 768;
    float v;
    if (r < 77)       v = context[((long)(1 + i) * 77 + r) * 768 + c];
    else if (r < 334) v = imgf[((long)i * 257 + (r - 77)) * 768 + c];
    else if (r == 334) v = boxtok[i * 768 + c];
    else v = 0.f;
    out[idx] = f2bf(v);
}
__global__ void assemble_bg(const float* __restrict__ context, const float* __restrict__ bgf,
                            bhalf* __restrict__ out){
    const int idx = blockIdx.x * 256 + threadIdx.x;
    if (idx >= 336 * 768) return;
    const int r = idx / 768, c = idx % 768;
    float v;
    if (r < 77)       v = context[(long)r * 768 + c];
    else if (r < 334) v = bgf[(long)(r - 77) * 768 + c];
    else v = 0.f;
    out[idx] = f2bf(v);
}

// ---------------------------------------------------------------- LayerNorm over C=320
__global__ __launch_bounds__(320) void ln_kernel(
    const float* __restrict__ in, const float* __restrict__ g, const float* __restrict__ b,
    bhalf* __restrict__ out)
{
    const int row = blockIdx.x, c = threadIdx.x;
    const float v = in[(long)row * 320 + c];
    float s = v, sq = v * v;
#pragma unroll
    for (int o = 1; o < 64; o <<= 1){ s += __shfl_xor(s, o); sq += __shfl_xor(sq, o); }
    __shared__ float rs[5], rq[5];
    const int wv = threadIdx.x >> 6;
    if ((threadIdx.x & 63) == 0){ rs[wv] = s; rq[wv] = sq; }
    __syncthreads();
    if (threadIdx.x == 0){
        float ts = 0, tq = 0;
#pragma unroll
        for (int w = 0; w < 5; ++w){ ts += rs[w]; tq += rq[w]; }
        rs[0] = ts; rq[0] = tq;
    }
    __syncthreads();
    const float mean = rs[0] * (1.f / 320.f);
    const float var  = rq[0] * (1.f / 320.f) - mean * mean;
    const float inv  = rsqrtf(var + 1e-5f);
    out[(long)row * 320 + c] = f2bf((v - mean) * inv * g[c] + b[c]);
}

// S = sum_i sig_i * (ca_x[1+i] + ea_i), then q2 = LN(S)
__global__ __launch_bounds__(320) void s_ln_kernel(
    const float* __restrict__ ca_x, const float* __restrict__ ea, const float* __restrict__ sig,
    const float* __restrict__ g, const float* __restrict__ b,
    float* __restrict__ S, bhalf* __restrict__ q2)
{
    const int hw = blockIdx.x, c = threadIdx.x;
    float v = 0.f;
#pragma unroll
    for (int i = 0; i < 4; ++i){
        const float sg = sig[i * 4096 + hw];
        v += sg * (ca_x[((long)(1 + i) * 4096 + hw) * 320 + c] + ea[((long)i * 4096 + hw) * 320 + c]);
    }
    S[(long)hw * 320 + c] = v;
    float s = v, sq = v * v;
#pragma unroll
    for (int o = 1; o < 64; o <<= 1){ s += __shfl_xor(s, o); sq += __shfl_xor(sq, o); }
    __shared__ float rs[5], rq[5];
    const int wv = threadIdx.x >> 6;
    if ((threadIdx.x & 63) == 0){ rs[wv] = s; rq[wv] = sq; }
    __syncthreads();
    if (threadIdx.x == 0){
        float ts = 0, tq = 0;
#pragma unroll
        for (int w = 0; w < 5; ++w){ ts += rs[w]; tq += rq[w]; }
        rs[0] = ts; rq[0] = tq;
    }
    __syncthreads();
    const float mean = rs[0] * (1.f / 320.f);
    const float var  = rq[0] * (1.f / 320.f) - mean * mean;
    const float inv  = rsqrtf(var + 1e-5f);
    q2[(long)hw * 320 + c] = f2bf((v - mean) * inv * g[c] + b[c]);
}

__global__ void f2bf_kernel(const float* __restrict__ in, bhalf* __restrict__ out, int n){
    const int i = blockIdx.x * 256 + threadIdx.x;
    if (i < n) out[i] = f2bf(in[i]);
}

// ---------------------------------------------------------------- generic GEMM: C[M][320] = A[M][K] @ Wt[320][K]^T
// MODE 0: bf16 out. 2: f32 out + bias. 3: f32 out = acc+bias+add1+add2. 4: f32 out += acc+bias.
template<int MODE>
__global__ __launch_bounds__(256) void gemm320(
    const bhalf* __restrict__ A, const bhalf* __restrict__ Wt,
    const float* __restrict__ bias, bhalf* __restrict__ Cbf,
    float* __restrict__ Cf, const float* __restrict__ add1, const float* __restrict__ add2,
    int M, int K)
{
    const int wave = threadIdx.x >> 6, lane = threadIdx.x & 63;
    const int m0 = blockIdx.x * 64 + wave * 16;
    const int n0 = blockIdx.y * 64;
    int mrow = m0 + (lane & 15); if (mrow > M - 1) mrow = M - 1;
    const int klo = (lane >> 4) * 8;
    const bhalf* ap = A + (long)mrow * K + klo;
    const bhalf* wp = Wt + (long)(n0 + (lane & 15)) * K + klo;
    const f32x4 fz = {0.f, 0.f, 0.f, 0.f};
    f32x4 acc[4]; acc[0] = fz; acc[1] = fz; acc[2] = fz; acc[3] = fz;
    for (int k0 = 0; k0 < K; k0 += 32){
        s16x8 a = *(const s16x8*)(ap + k0);
#pragma unroll
        for (int t = 0; t < 4; ++t){
            s16x8 b = *(const s16x8*)(wp + (long)t * 16 * K + k0);
            acc[t] = __builtin_amdgcn_mfma_f32_16x16x32_bf16(a, b, acc[t], 0, 0, 0);
        }
    }
    const int rb = m0 + (lane >> 4) * 4;
#pragma unroll
    for (int t = 0; t < 4; ++t){
        const int col = n0 + t * 16 + (lane & 15);
#pragma unroll
        for (int r = 0; r < 4; ++r){
            const int row = rb + r;
            if (row >= M) continue;
            const float v = acc[t][r];
            if (MODE == 0) Cbf[(long)row * 320 + col] = f2bf(v);
            else if (MODE == 2) Cf[(long)row * 320 + col] = v + bias[col];
            else if (MODE == 3){ const long o = (long)row * 320 + col; Cf[o] = v + bias[col] + add1[o] + add2[o]; }
            else { const long o = (long)row * 320 + col; Cf[o] += v + bias[col]; }
        }
    }
}

// ---------------------------------------------------------------- V-transpose GEMM: Vt[n][m] via LDS-transposed epilogue
__global__ __launch_bounds__(256) void gemm_vt(
    const bhalf* __restrict__ A, const bhalf* __restrict__ Wt, bhalf* __restrict__ Vt,
    int M, int K, long a_zs, long vt_zs, int vt_ns)
{
    A  += blockIdx.z * a_zs;
    Vt += blockIdx.z * vt_zs;
    const int wave = threadIdx.x >> 6, lane = threadIdx.x & 63;
    const int m0 = blockIdx.x * 64 + wave * 16;
    const int n0 = blockIdx.y * 64;
    int mrow = m0 + (lane & 15); if (mrow > M - 1) mrow = M - 1;
    const int klo = (lane >> 4) * 8;
    const bhalf* ap = A + (long)mrow * K + klo;
    const bhalf* wp = Wt + (long)(n0 + (lane & 15)) * K + klo;
    const f32x4 fz = {0.f, 0.f, 0.f, 0.f};
    f32x4 acc[4]; acc[0] = fz; acc[1] = fz; acc[2] = fz; acc[3] = fz;
    for (int k0 = 0; k0 < K; k0 += 32){
        s16x8 a = *(const s16x8*)(ap + k0);
#pragma unroll
        for (int t = 0; t < 4; ++t){
            s16x8 b = *(const s16x8*)(wp + (long)t * 16 * K + k0);
            acc[t] = __builtin_amdgcn_mfma_f32_16x16x32_bf16(a, b, acc[t], 0, 0, 0);
        }
    }
    __shared__ bhalf T[64][72];
    const int hi = lane >> 4, l15 = lane & 15;
#pragma unroll
    for (int t = 0; t < 4; ++t)
#pragma unroll
        for (int r = 0; r < 4; ++r)
            T[wave * 16 + hi * 4 + r][t * 16 + l15] = f2bf(acc[t][r]);
    __syncthreads();
    const int c = threadIdx.x & 63, jq = threadIdx.x >> 6;
    const int jbase = blockIdx.x * 64 + jq * 16;
    if (jbase >= M) return;
    u32 wb[8];
#pragma unroll
    for (int p = 0; p < 8; ++p)
        wb[p] = (u32)T[jq * 16 + 2 * p][c] | ((u32)T[jq * 16 + 2 * p + 1][c] << 16);
    bhalf* vp = Vt + (long)(n0 + c) * vt_ns + jbase;
    if (jbase + 16 <= M){
        *(uint4*)vp       = make_uint4(wb[0], wb[1], wb[2], wb[3]);
        *(uint4*)(vp + 8) = make_uint4(wb[4], wb[5], wb[6], wb[7]);
    } else {
        for (int jj = 0; jj < 16 && jbase + jj < M; ++jj)
            vp[jj] = T[jq * 16 + jj][c];
    }
}

// ---------------------------------------------------------------- flash attention: register softmax, no LDS, no barriers
// PARTIAL: blockIdx.z = kv-partition g (16 chunks of 64 each); writes unnormalized acc + (m,l).
template<bool GMM, bool PARTIAL>
__global__ __launch_bounds__(256) void flash2(
    const bhalf* __restrict__ Q, const bhalf* __restrict__ Kc, const bhalf* __restrict__ Vt,
    bhalf* __restrict__ O, const u64* __restrict__ maskb,
    int NKV, long q_is, long k_is, long vt_is, int vt_ns,
    float* __restrict__ pacc, float* __restrict__ pml)
{
    const int lane = threadIdx.x & 63, wave = threadIdx.x >> 6;
    const int l15 = lane & 15, hi = lane >> 4, klo = hi * 8;
    const int h = blockIdx.y;
    const int inst = PARTIAL ? 0 : blockIdx.z;
    const int g = PARTIAL ? blockIdx.z : 0;
    const int q = blockIdx.x * 64 + wave * 16 + l15;
    const s16x8 z8 = {0, 0, 0, 0, 0, 0, 0, 0};
    const f32x4 fz = {0.f, 0.f, 0.f, 0.f};

    const bhalf* qp = Q + inst * q_is + (long)q * 320 + h * 40;
    const s16x8 qb0 = *(const s16x8*)(qp + klo);
    const s16x8 qb1 = (hi == 0) ? *(const s16x8*)(qp + 32) : z8;

    const int krbase = 8 * (l15 >> 2) + (l15 & 3);
    const bhalf* kbase = Kc + inst * k_is + h * 40 + (long)krbase * 320;

    const bhalf* vbase[3];
#pragma unroll
    for (int ct = 0; ct < 3; ++ct){
        int dr = h * 40 + ct * 16 + l15; if (dr > 319) dr = 319;
        vbase[ct] = Vt + inst * vt_is + (long)dr * vt_ns + hi * 8;
    }

    f32x4 acc[3]; acc[0] = fz; acc[1] = fz; acc[2] = fz;
    float m_run = NEG_INF, l_run = 0.f;

    auto soft_pv = [&](f32x4 (&d)[4], int c0){
        float cmax = NEG_INF;
#pragma unroll
        for (int t = 0; t < 4; ++t)
#pragma unroll
            for (int r = 0; r < 4; ++r) cmax = fmaxf(cmax, d[t][r]);
        cmax = fmaxf(cmax, __shfl_xor(cmax, 16));
        cmax = fmaxf(cmax, __shfl_xor(cmax, 32));
        const float mnew = fmaxf(m_run, cmax);
        const float fac = fexp2((m_run - mnew) * K2E);
        const float negm = -mnew * K2E;
        float csum = 0.f;
#pragma unroll
        for (int t = 0; t < 4; ++t)
#pragma unroll
            for (int r = 0; r < 4; ++r){
                const float p = fexp2(fmaf(d[t][r], K2E, negm));
                d[t][r] = p; csum += p;
            }
        csum += __shfl_xor(csum, 16);
        csum += __shfl_xor(csum, 32);
        l_run = l_run * fac + csum;
        m_run = mnew;
#pragma unroll
        for (int ct = 0; ct < 3; ++ct)
#pragma unroll
            for (int r = 0; r < 4; ++r) acc[ct][r] *= fac;
#pragma unroll
        for (int s = 0; s < 2; ++s){
            union { u32 w[4]; s16x8 v; } pb;
            pb.w[0] = cvtpk(d[2 * s][0], d[2 * s][1]);
            pb.w[1] = cvtpk(d[2 * s][2], d[2 * s][3]);
            pb.w[2] = cvtpk(d[2 * s + 1][0], d[2 * s + 1][1]);
            pb.w[3] = cvtpk(d[2 * s + 1][2], d[2 * s + 1][3]);
#pragma unroll
            for (int ct = 0; ct < 3; ++ct){
                const s16x8 va = *(const s16x8*)(vbase[ct] + c0 + 32 * s);
                acc[ct] = __builtin_amdgcn_mfma_f32_16x16x32_bf16(va, pb.v, acc[ct], 0, 0, 0);
            }
        }
    };

    const int ch0 = PARTIAL ? (g << 4) : 0;
    const int chN = PARTIAL ? (ch0 + 16) : (NKV >> 6);
    for (int ch = ch0; ch < chN; ++ch){
        const int c0 = ch << 6;
        u64 M = ~0ull;
        if (GMM){
            M = maskb[(long)q * 64 + ch];
            if (__all(M == 0)) continue;
        }
        f32x4 d[4];
#pragma unroll
        for (int t = 0; t < 4; ++t){
            const int toff = ((t >> 1) << 5) + ((t & 1) << 2);
            const bhalf* kp = kbase + (long)(c0 + toff) * 320;
            const s16x8 k0 = *(const s16x8*)(kp + klo);
            const s16x8 k1 = (hi == 0) ? *(const s16x8*)(kp + 32) : z8;
            d[t] = __builtin_amdgcn_mfma_f32_16x16x32_bf16(k0, qb0, fz, 0, 0, 0);
            d[t] = __builtin_amdgcn_mfma_f32_16x16x32_bf16(k1, qb1, d[t], 0, 0, 0);
        }
        if (GMM && !__all(M == ~0ull)){
            const u64 Mh = M >> (hi * 8);
#pragma unroll
            for (int t = 0; t < 4; ++t){
                const int tb = ((t >> 1) << 5) + ((t & 1) << 2);
#pragma unroll
                for (int r = 0; r < 4; ++r)
                    if (!((Mh >> (tb + r)) & 1)) d[t][r] = NEG_INF;
            }
        }
        soft_pv(d, c0);
    }
    if (!PARTIAL && (NKV & 63)){
        const int c0 = (NKV >> 6) << 6;
        f32x4 d[4];
#pragma unroll
        for (int t = 0; t < 4; ++t){
            const int toff = ((t >> 1) << 5) + ((t & 1) << 2);
            int kr = c0 + toff + krbase; if (kr > NKV - 1) kr = NKV - 1;
            const bhalf* kp = Kc + inst * k_is + h * 40 + (long)kr * 320;
            const s16x8 k0 = *(const s16x8*)(kp + klo);
            const s16x8 k1 = (hi == 0) ? *(const s16x8*)(kp + 32) : z8;
            d[t] = __builtin_amdgcn_mfma_f32_16x16x32_bf16(k0, qb0, fz, 0, 0, 0);
            d[t] = __builtin_amdgcn_mfma_f32_16x16x32_bf16(k1, qb1, d[t], 0, 0, 0);
        }
#pragma unroll
        for (int t = 0; t < 4; ++t){
            const int tb = ((t >> 1) << 5) + ((t & 1) << 2);
#pragma unroll
            for (int r = 0; r < 4; ++r)
                if (c0 + tb + hi * 8 + r >= NKV) d[t][r] = NEG_INF;
        }
        soft_pv(d, c0);
    }

    if (PARTIAL){
        // coalesced partial store: [g][h][ct][hi][q][4] f32 (adjacent-q lanes contiguous)
#pragma unroll
        for (int ct = 0; ct < 3; ++ct)
            *(f32x4*)(pacc + ((((size_t)(g * 8 + h) * 3 + ct) * 4 + hi) * 4096 + q) * 4) = acc[ct];
        if (hi == 0){
            pml[((size_t)(g * 8 + h) * 4096 + q) * 2]     = m_run;
            pml[((size_t)(g * 8 + h) * 4096 + q) * 2 + 1] = l_run;
        }
    } else {
        const float inv = 1.f / l_run;
        bhalf* op = O + inst * q_is + (long)q * 320 + h * 40;
#pragma unroll
        for (int ct = 0; ct < 3; ++ct){
            const int d0 = ct * 16 + hi * 4;
            if (d0 < 40){
                uint2 w;
                w.x = cvtpk(acc[ct][0] * inv, acc[ct][1] * inv);
                w.y = cvtpk(acc[ct][2] * inv, acc[ct][3] * inv);
                *(uint2*)(op + d0) = w;
            }
        }
    }
}

// ---------------------------------------------------------------- combine kv-split partials -> O
__global__ __launch_bounds__(256) void combine_kernel(
    const float* __restrict__ pacc, const float* __restrict__ pml, bhalf* __restrict__ O)
{
    const int idx = blockIdx.x * 256 + threadIdx.x;  // 4096*8
    const int h = idx >> 12, q = idx & 4095;
    float m[4], l[4];
#pragma unroll
    for (int g = 0; g < 4; ++g){
        m[g] = pml[((size_t)(g * 8 + h) * 4096 + q) * 2];
        l[g] = pml[((size_t)(g * 8 + h) * 4096 + q) * 2 + 1];
    }
    const float ms = fmaxf(fmaxf(m[0], m[1]), fmaxf(m[2], m[3]));
    float acc[48];
#pragma unroll
    for (int d = 0; d < 48; ++d) acc[d] = 0.f;
    float ls = 0.f;
#pragma unroll
    for (int g = 0; g < 4; ++g){
        const float w = fexp2((m[g] - ms) * K2E);
        ls += l[g] * w;
#pragma unroll
        for (int ct = 0; ct < 3; ++ct)
#pragma unroll
            for (int hi = 0; hi < 4; ++hi){
                const f32x4 v = *(const f32x4*)(pacc + ((((size_t)(g * 8 + h) * 3 + ct) * 4 + hi) * 4096 + q) * 4);
#pragma unroll
                for (int r = 0; r < 4; ++r) acc[ct * 16 + hi * 4 + r] += v[r] * w;
            }
    }
    const float inv = 1.f / ls;
    u32 wb[20];
#pragma unroll
    for (int d = 0; d < 20; ++d) wb[d] = cvtpk(acc[2 * d] * inv, acc[2 * d + 1] * inv);
    uint4* op = (uint4*)(O + (size_t)q * 320 + h * 40);
#pragma unroll
    for (int p = 0; p < 5; ++p)
        op[p] = make_uint4(wb[4 * p], wb[4 * p + 1], wb[4 * p + 2], wb[4 * p + 3]);
}

// ================================================================ host
extern "C" void kernel_launch(void* const* d_in, const int* in_sizes, int n_in,
                              void* d_out, int out_size, void* d_ws, size_t ws_size,
                              hipStream_t stream)
{
    (void)in_sizes; (void)n_in; (void)out_size; (void)ws_size;
    const float* ca_x   = (const float*)d_in[0];
    const float* gmask  = (const float*)d_in[1];
    const float* smask  = (const float*)d_in[2];
    const float* itok   = (const float*)d_in[3];
    const float* ctx    = (const float*)d_in[4];
    const float* box    = (const float*)d_in[5];
    const float* imgf   = (const float*)d_in[6];
    const float* bgf    = (const float*)d_in[7];
    const float* sgv    = (const float*)d_in[8];
    const float* Wq_obj = (const float*)d_in[9];
    const float* Wk_obj = (const float*)d_in[10];
    const float* Wv_obj = (const float*)d_in[11];
    const float* Wo_obj = (const float*)d_in[12];
    const float* bo_obj = (const float*)d_in[13];
    const float* g_obj  = (const float*)d_in[14];
    const float* b_obj  = (const float*)d_in[15];
    const float* Wq2    = (const float*)d_in[16];
    const float* Wk2    = (const float*)d_in[17];
    const float* Wv2    = (const float*)d_in[18];
    const float* Wo2    = (const float*)d_in[19];
    const float* bo2    = (const float*)d_in[20];
    const float* g2     = (const float*)d_in[21];
    const float* b2     = (const float*)d_in[22];
    const float* pnW1   = (const float*)d_in[23];
    const float* pnb1   = (const float*)d_in[24];
    const float* pnW2   = (const float*)d_in[25];
    const float* pnb2   = (const float*)d_in[26];
    const float* pnW3   = (const float*)d_in[27];
    const float* pnb3   = (const float*)d_in[28];
    const float* laWq   = (const float*)d_in[29];
    const float* laWk   = (const float*)d_in[30];
    const float* laWv   = (const float*)d_in[31];
    const float* laWo   = (const float*)d_in[32];
    const float* labo   = (const float*)d_in[33];

    char* wsp = (char*)d_ws; size_t off = 0;
    auto alloc = [&](size_t bytes) -> void* {
        void* p = wsp + off; off += (bytes + 255) & ~(size_t)255; return p;
    };
    bhalf* wqobjT = (bhalf*)alloc(320 * 320 * 2);
    bhalf* woobjT = (bhalf*)alloc(320 * 320 * 2);
    bhalf* wq2T   = (bhalf*)alloc(320 * 320 * 2);
    bhalf* wo2T   = (bhalf*)alloc(320 * 320 * 2);
    bhalf* lawqT  = (bhalf*)alloc(320 * 320 * 2);
    bhalf* lawkT  = (bhalf*)alloc(320 * 320 * 2);
    bhalf* lawvT  = (bhalf*)alloc(320 * 320 * 2);
    bhalf* lawoT  = (bhalf*)alloc(320 * 320 * 2);
    bhalf* wkobjT = (bhalf*)alloc(768 * 320 * 2);
    bhalf* wvobjT = (bhalf*)alloc(768 * 320 * 2);
    bhalf* wk2T   = (bhalf*)alloc(768 * 320 * 2);
    bhalf* wv2T   = (bhalf*)alloc(768 * 320 * 2);
    float* gm_all = (float*)alloc(5 * 4096 * 4);
    float* sig    = (float*)alloc(4 * 4096 * 4);
    float* boxtok = (float*)alloc(4 * 768 * 4);
    u64*   maskb  = (u64*)alloc((size_t)4096 * 64 * 8);
    bhalf* ctx_fg = (bhalf*)alloc((size_t)4 * 336 * 768 * 2);
    bhalf* ctx_bg = (bhalf*)alloc((size_t)336 * 768 * 2);
    bhalf* q_in   = (bhalf*)alloc((size_t)16384 * 320 * 2);
    bhalf* x_la   = (bhalf*)alloc((size_t)4096 * 320 * 2);
    bhalf* k_obj  = (bhalf*)alloc((size_t)4 * 336 * 320 * 2);
    bhalf* vt_obj = (bhalf*)alloc((size_t)4 * 320 * 384 * 2);
    bhalf* k_bg   = (bhalf*)alloc((size_t)336 * 320 * 2);
    bhalf* vt_bg  = (bhalf*)alloc((size_t)320 * 384 * 2);
    bhalf* q_obj  = (bhalf*)alloc((size_t)16384 * 320 * 2);
    bhalf* o_obj  = (bhalf*)alloc((size_t)16384 * 320 * 2);
    float* ea     = (float*)alloc((size_t)16384 * 320 * 4);
    float* Sbuf   = (float*)alloc((size_t)4096 * 320 * 4);
    bhalf* q2v    = (bhalf*)alloc((size_t)4096 * 320 * 2);
    bhalf* q2p    = (bhalf*)alloc((size_t)4096 * 320 * 2);
    bhalf* o2     = (bhalf*)alloc((size_t)4096 * 320 * 2);
    bhalf* ql     = (bhalf*)alloc((size_t)4096 * 320 * 2);
    bhalf* kl     = (bhalf*)alloc((size_t)4096 * 320 * 2);
    bhalf* vt_l   = (bhalf*)alloc((size_t)320 * 4096 * 2);
    bhalf* ol     = (bhalf*)alloc((size_t)4096 * 320 * 2);

    // kv-split partials ALIAS dead region (q_in..o_obj all fully consumed before layout flash):
    // pacc: 4*8*3*4*4096*4 f32 = 25.2 MB, pml: 4*8*4096*2 f32 = 1 MB; region spans ~36 MB. 
    float* pacc = (float*)q_in;
    float* pml  = pacc + (size_t)4 * 8 * 3 * 4 * 4096 * 4;

    WB8 wa{};
    wa.in[0] = Wq_obj; wa.out[0] = wqobjT;
    wa.in[1] = Wo_obj; wa.out[1] = woobjT;
    wa.in[2] = Wq2;    wa.out[2] = wq2T;
    wa.in[3] = Wo2;    wa.out[3] = wo2T;
    wa.in[4] = laWq;   wa.out[4] = lawqT;
    wa.in[5] = laWk;   wa.out[5] = lawkT;
    wa.in[6] = laWv;   wa.out[6] = lawvT;
    wa.in[7] = laWo;   wa.out[7] = lawoT;
    transpose_w<<<dim3((8 * 320 * 320 + 255) / 256), 256, 0, stream>>>(wa, 320, 8);
    WB8 wb{};
    wb.in[0] = Wk_obj; wb.out[0] = wkobjT;
    wb.in[1] = Wv_obj; wb.out[1] = wvobjT;
    wb.in[2] = Wk2;    wb.out[2] = wk2T;
    wb.in[3] = Wv2;    wb.out[3] = wv2T;
    transpose_w<<<dim3((4 * 768 * 320 + 255) / 256), 256, 0, stream>>>(wb, 768, 4);

    resize_kernel<<<dim3(16), 256, 0, stream>>>(gmask, smask, sgv, gm_all, sig);
    maskbits_kernel<<<dim3(64, 4), 256, 0, stream>>>(gm_all, maskb);
    posnet_kernel<<<dim3(4), 768, 0, stream>>>(box, pnW1, pnb1, pnW2, pnb2, pnW3, pnb3, boxtok);
    assemble_fg<<<dim3((4 * 336 * 768 + 255) / 256), 256, 0, stream>>>(ctx, imgf, boxtok, ctx_fg);
    assemble_bg<<<dim3((336 * 768 + 255) / 256), 256, 0, stream>>>(ctx, bgf, ctx_bg);
    ln_kernel<<<dim3(16384), 320, 0, stream>>>(itok + (size_t)4096 * 320, g_obj, b_obj, q_in);
    f2bf_kernel<<<dim3((4096 * 320 + 255) / 256), 256, 0, stream>>>(itok, x_la, 4096 * 320);

    // zero Vt pad columns (cols NKV..383) so P=0 x pad is exact
    hipMemsetAsync(vt_obj, 0, (size_t)4 * 320 * 384 * 2, stream);
    hipMemsetAsync(vt_bg, 0, (size_t)320 * 384 * 2, stream);

    // K/V projections
    gemm320<0><<<dim3(21, 5), 256, 0, stream>>>(ctx_fg, wkobjT, nullptr, k_obj, nullptr, nullptr, nullptr, 1344, 768);
    gemm_vt<<<dim3(6, 5, 4), 256, 0, stream>>>(ctx_fg, wvobjT, vt_obj, 336, 768, (long)336 * 768, (long)320 * 384, 384);
    gemm320<0><<<dim3(6, 5), 256, 0, stream>>>(ctx_bg, wk2T, nullptr, k_bg, nullptr, nullptr, nullptr, 336, 768);
    gemm_vt<<<dim3(6, 5, 1), 256, 0, stream>>>(ctx_bg, wv2T, vt_bg, 336, 768, 0, 0, 384);

    // ea_obj: Q-proj, attention, O-proj
    gemm320<0><<<dim3(256, 5), 256, 0, stream>>>(q_in, wqobjT, nullptr, q_obj, nullptr, nullptr, nullptr, 16384, 320);
    flash2<false, false><<<dim3(64, 8, 4), 256, 0, stream>>>(q_obj, k_obj, vt_obj, o_obj, nullptr,
        335, (long)4096 * 320, (long)336 * 320, (long)320 * 384, 384, nullptr, nullptr);
    gemm320<2><<<dim3(256, 5), 256, 0, stream>>>(o_obj, woobjT, bo_obj, nullptr, ea, nullptr, nullptr, 16384, 320);

    // S = sum_i sig*(ca_x[1+i]+ea_i); q2 = LN(S)
    s_ln_kernel<<<dim3(4096), 320, 0, stream>>>(ca_x, ea, sig, g2, b2, Sbuf, q2v);

    // ea2 (background)
    gemm320<0><<<dim3(64, 5), 256, 0, stream>>>(q2v, wq2T, nullptr, q2p, nullptr, nullptr, nullptr, 4096, 320);
    flash2<false, false><<<dim3(64, 8, 1), 256, 0, stream>>>(q2p, k_bg, vt_bg, o2, nullptr,
        334, 0, 0, 0, 384, nullptr, nullptr);

    // layout self-attention with gm-mask, kv-split G=4 (NOTE: partials alias q_in.. region — dead here)
    gemm320<0><<<dim3(64, 5), 256, 0, stream>>>(x_la, lawqT, nullptr, ql, nullptr, nullptr, nullptr, 4096, 320);
    gemm320<0><<<dim3(64, 5), 256, 0, stream>>>(x_la, lawkT, nullptr, kl, nullptr, nullptr, nullptr, 4096, 320);
    gemm_vt<<<dim3(64, 5, 1), 256, 0, stream>>>(x_la, lawvT, vt_l, 4096, 320, 0, 0, 4096);
    flash2<true, true><<<dim3(64, 8, 4), 256, 0, stream>>>(ql, kl, vt_l, nullptr, maskb,
        4096, 0, 0, 0, 4096, pacc, pml);
    combine_kernel<<<dim3(128), 256, 0, stream>>>(pacc, pml, ol);

    // out = ca_x[0] + S + ea_bg  (+ fusion)
    gemm320<3><<<dim3(64, 5), 256, 0, stream>>>(o2, wo2T, bo2, nullptr, (float*)d_out, ca_x, Sbuf, 4096, 320);
    gemm320<4><<<dim3(64, 5), 256, 0, stream>>>(ol, lawoT, labo, nullptr, (float*)d_out, nullptr, nullptr, 4096, 320);
}